// Round 2
// baseline (497.335 us; speedup 1.0000x reference)
//
#include <hip/hip_runtime.h>
#include <cstdint>
#include <cstddef>

// Problem constants: B=2, S=512, D_MODEL=512, H=8, dk=64, N_SAMPLES=16
// R = B*H*S = 8192 rows; total uniforms = R*16*512 = 2^26.
// JAX (threefry_partitionable=True, default since 0.5.0):
//   bits[i] = o0 ^ o1 where (o0,o1) = threefry2x32(key=(0,42), x=(hi32(i), lo32(i)))
//   u[i] = bitcast((bits[i]>>9)|0x3f800000) - 1.0 ;  s = u < p

// ---------------------------------------------------------------------------
// Threefry-2x32 with key = (0, 42)  (jax.random.key(42)), 20 rounds.
// ks = [0, 42, 0x1BD11BDA ^ 0 ^ 42 = 0x1BD11BF0]
// ---------------------------------------------------------------------------
__device__ __forceinline__ void threefry_0_42(uint32_t x0, uint32_t x1,
                                              uint32_t &o0, uint32_t &o1) {
  const uint32_t K1 = 42u;
  const uint32_t K2 = 0x1BD11BF0u;
  x1 += K1;                       // x0 += ks[0] == 0
#define TFR(r) { x0 += x1; x1 = ((x1 << (r)) | (x1 >> (32 - (r)))); x1 ^= x0; }
  TFR(13) TFR(15) TFR(26) TFR(6)
  x0 += K1; x1 += K2 + 1u;
  TFR(17) TFR(29) TFR(16) TFR(24)
  x0 += K2; x1 += 2u;             // + ks[0] + 2
  TFR(13) TFR(15) TFR(26) TFR(6)
  x1 += K1 + 3u;                  // x0 += ks[0]
  TFR(17) TFR(29) TFR(16) TFR(24)
  x0 += K1; x1 += K2 + 4u;
  TFR(13) TFR(15) TFR(26) TFR(6)
  x0 += K2; x1 += 5u;             // + ks[0] + 5
#undef TFR
  o0 = x0; o1 = x1;
}

// ---------------------------------------------------------------------------
// Kernel A: QKV projection.  out[b,h,s,d] = (x @ W + bias)   (f32 tiled GEMM)
// grid = (16, 8, 3), block = 256.  BM=BN=64, BK=16, 4x4 per thread.
// ---------------------------------------------------------------------------
__global__ __launch_bounds__(256)
void qkv_gemm(const float* __restrict__ x,
              const float* __restrict__ Wq, const float* __restrict__ bq,
              const float* __restrict__ Wk, const float* __restrict__ bk,
              const float* __restrict__ Wv, const float* __restrict__ bv,
              float* __restrict__ Qw, float* __restrict__ Kw,
              float* __restrict__ Vw) {
  const float* W; const float* bias; float* out;
  if (blockIdx.z == 0)      { W = Wq; bias = bq; out = Qw; }
  else if (blockIdx.z == 1) { W = Wk; bias = bk; out = Kw; }
  else                      { W = Wv; bias = bv; out = Vw; }

  __shared__ float As[64][17];
  __shared__ float Bs[16][64];
  const int tid = threadIdx.x;
  const int tx = tid & 15, ty = tid >> 4;
  const int row0 = blockIdx.x * 64, col0 = blockIdx.y * 64;
  float acc[4][4] = {};

  for (int kk = 0; kk < 512; kk += 16) {
#pragma unroll
    for (int i = 0; i < 4; ++i) {
      int idx = tid + i * 256;
      As[idx >> 4][idx & 15] =
          x[(size_t)(row0 + (idx >> 4)) * 512 + kk + (idx & 15)];
      Bs[idx >> 6][idx & 63] =
          W[(size_t)(kk + (idx >> 6)) * 512 + col0 + (idx & 63)];
    }
    __syncthreads();
#pragma unroll
    for (int p = 0; p < 16; ++p) {
      float a0 = As[ty * 4 + 0][p], a1 = As[ty * 4 + 1][p];
      float a2 = As[ty * 4 + 2][p], a3 = As[ty * 4 + 3][p];
      float4 b4 = *(const float4*)&Bs[p][tx * 4];
      acc[0][0] = fmaf(a0, b4.x, acc[0][0]); acc[0][1] = fmaf(a0, b4.y, acc[0][1]);
      acc[0][2] = fmaf(a0, b4.z, acc[0][2]); acc[0][3] = fmaf(a0, b4.w, acc[0][3]);
      acc[1][0] = fmaf(a1, b4.x, acc[1][0]); acc[1][1] = fmaf(a1, b4.y, acc[1][1]);
      acc[1][2] = fmaf(a1, b4.z, acc[1][2]); acc[1][3] = fmaf(a1, b4.w, acc[1][3]);
      acc[2][0] = fmaf(a2, b4.x, acc[2][0]); acc[2][1] = fmaf(a2, b4.y, acc[2][1]);
      acc[2][2] = fmaf(a2, b4.z, acc[2][2]); acc[2][3] = fmaf(a2, b4.w, acc[2][3]);
      acc[3][0] = fmaf(a3, b4.x, acc[3][0]); acc[3][1] = fmaf(a3, b4.y, acc[3][1]);
      acc[3][2] = fmaf(a3, b4.z, acc[3][2]); acc[3][3] = fmaf(a3, b4.w, acc[3][3]);
    }
    __syncthreads();
  }
#pragma unroll
  for (int i = 0; i < 4; ++i) {
    int row = row0 + ty * 4 + i;
    int b = row >> 9, s = row & 511;
#pragma unroll
    for (int j = 0; j < 4; ++j) {
      int col = col0 + tx * 4 + j;
      int h = col >> 6, d = col & 63;
      out[(((size_t)(b * 8 + h) * 512 + s) * 64) + d] = acc[i][j] + bias[col];
    }
  }
}

// ---------------------------------------------------------------------------
// Kernel D: output projection.  C[1024,512] = A @ Wo + bo  (plain row-major)
// ---------------------------------------------------------------------------
__global__ __launch_bounds__(256)
void out_gemm(const float* __restrict__ A, const float* __restrict__ W,
              const float* __restrict__ bias, float* __restrict__ C) {
  __shared__ float As[64][17];
  __shared__ float Bs[16][64];
  const int tid = threadIdx.x;
  const int tx = tid & 15, ty = tid >> 4;
  const int row0 = blockIdx.x * 64, col0 = blockIdx.y * 64;
  float acc[4][4] = {};

  for (int kk = 0; kk < 512; kk += 16) {
#pragma unroll
    for (int i = 0; i < 4; ++i) {
      int idx = tid + i * 256;
      As[idx >> 4][idx & 15] =
          A[(size_t)(row0 + (idx >> 4)) * 512 + kk + (idx & 15)];
      Bs[idx >> 6][idx & 63] =
          W[(size_t)(kk + (idx >> 6)) * 512 + col0 + (idx & 63)];
    }
    __syncthreads();
#pragma unroll
    for (int p = 0; p < 16; ++p) {
      float a0 = As[ty * 4 + 0][p], a1 = As[ty * 4 + 1][p];
      float a2 = As[ty * 4 + 2][p], a3 = As[ty * 4 + 3][p];
      float4 b4 = *(const float4*)&Bs[p][tx * 4];
      acc[0][0] = fmaf(a0, b4.x, acc[0][0]); acc[0][1] = fmaf(a0, b4.y, acc[0][1]);
      acc[0][2] = fmaf(a0, b4.z, acc[0][2]); acc[0][3] = fmaf(a0, b4.w, acc[0][3]);
      acc[1][0] = fmaf(a1, b4.x, acc[1][0]); acc[1][1] = fmaf(a1, b4.y, acc[1][1]);
      acc[1][2] = fmaf(a1, b4.z, acc[1][2]); acc[1][3] = fmaf(a1, b4.w, acc[1][3]);
      acc[2][0] = fmaf(a2, b4.x, acc[2][0]); acc[2][1] = fmaf(a2, b4.y, acc[2][1]);
      acc[2][2] = fmaf(a2, b4.z, acc[2][2]); acc[2][3] = fmaf(a2, b4.w, acc[2][3]);
      acc[3][0] = fmaf(a3, b4.x, acc[3][0]); acc[3][1] = fmaf(a3, b4.y, acc[3][1]);
      acc[3][2] = fmaf(a3, b4.z, acc[3][2]); acc[3][3] = fmaf(a3, b4.w, acc[3][3]);
    }
    __syncthreads();
  }
#pragma unroll
  for (int i = 0; i < 4; ++i) {
    int row = row0 + ty * 4 + i;
#pragma unroll
    for (int j = 0; j < 4; ++j) {
      int col = col0 + tx * 4 + j;
      C[(size_t)row * 512 + col] = acc[i][j] + bias[col];
    }
  }
}

// ---------------------------------------------------------------------------
// Kernel B: scores + softmax -> target (tf).  One block per row r = bh*512+q.
// ---------------------------------------------------------------------------
__global__ __launch_bounds__(256)
void scores_softmax(const float* __restrict__ Q, const float* __restrict__ Kt,
                    float* __restrict__ tf_g) {
  const int r = blockIdx.x;          // 0..8191
  const int bh = r >> 9, q = r & 511;
  const int tid = threadIdx.x;
  __shared__ __align__(16) float qs[64];
  __shared__ float red[8];
  if (tid < 64) qs[tid] = Q[((size_t)bh * 512 + q) * 64 + tid];
  __syncthreads();

  float sc[2];
#pragma unroll
  for (int ii = 0; ii < 2; ++ii) {
    const int k = tid + ii * 256;
    const float4* Kp = (const float4*)(Kt + ((size_t)bh * 512 + k) * 64);
    const float4* Qp = (const float4*)qs;
    float s = 0.f;
#pragma unroll
    for (int d4 = 0; d4 < 16; ++d4) {
      float4 kv = Kp[d4], qv = Qp[d4];
      s += qv.x * kv.x; s += qv.y * kv.y; s += qv.z * kv.z; s += qv.w * kv.w;
    }
    sc[ii] = s * 0.125f;   // SCALE = 1/sqrt(64); BETA = 1.0
  }
  float mx = fmaxf(sc[0], sc[1]);
  for (int m = 1; m < 64; m <<= 1) mx = fmaxf(mx, __shfl_xor(mx, m));
  if ((tid & 63) == 0) red[tid >> 6] = mx;
  __syncthreads();
  const float rowmax = fmaxf(fmaxf(red[0], red[1]), fmaxf(red[2], red[3]));
  const float e0 = expf(sc[0] - rowmax);
  const float e1 = expf(sc[1] - rowmax);
  float ssum = e0 + e1;
  for (int m = 1; m < 64; m <<= 1) ssum += __shfl_xor(ssum, m);
  if ((tid & 63) == 0) red[4 + (tid >> 6)] = ssum;
  __syncthreads();
  const float tot = red[4] + red[5] + red[6] + red[7];
  tf_g[(size_t)r * 512 + tid]       = e0 / tot;
  tf_g[(size_t)r * 512 + tid + 256] = e1 / tot;
}

// ---------------------------------------------------------------------------
// Kernel C: importance sampling + weighted-avg + attn @ V.
// One block per row r.  256 threads = 16 samples x 16 lanes; each lane covers
// k = t + 16*j, j<32.  Partitionable threefry: per-element counter (0, i).
// ---------------------------------------------------------------------------
__global__ __launch_bounds__(256)
void sample_attnv(const float* __restrict__ tf_g, const float* __restrict__ V,
                  float* __restrict__ ao) {
  const int r = blockIdx.x;                   // 0..8191
  const int b = r >> 12, h = (r >> 9) & 7, q = r & 511;
  const int tid = threadIdx.x;
  __shared__ float tf[512];
  __shared__ float wa[512];
  __shared__ float wr[16];
  __shared__ float redc[4];
  __shared__ float psum[4][64];

  for (int k = tid; k < 512; k += 256) {
    tf[k] = tf_g[(size_t)r * 512 + k];
    wa[k] = 0.f;
  }
  __syncthreads();

  const int n = tid >> 4, t = tid & 15;
  // flat element index i = r*8192 + n*512 + k,  k = t + 16*j   (i < 2^26)
  const uint32_t base = (uint32_t)r * 8192u + (uint32_t)n * 512u + (uint32_t)t;
  float pp = 1.f, pt = 1.f;
  int c = 0;
  uint32_t bits = 0u;
#pragma unroll 4
  for (int j = 0; j < 32; ++j) {
    const int k = t + (j << 4);
    uint32_t o0, o1;
    threefry_0_42(0u, base + (uint32_t)(j << 4), o0, o1);
    const uint32_t rb = o0 ^ o1;                       // partitionable fold
    const float u = __uint_as_float((rb >> 9) | 0x3f800000u) - 1.0f;
    const float tv = tf[k];
    const float p = 0.5f * tv + 0.0009765625f;  // prop = 0.5*target + 0.5/512
    const bool s = u < p;
    pp *= s ? p : (1.0f - p);
    pt *= s ? tv : 1.0f;
    c += s ? 1 : 0;
    bits |= (s ? 1u : 0u) << j;
  }
  // reduce products / counts over the 16 lanes of this sample
#pragma unroll
  for (int m = 1; m < 16; m <<= 1) {
    pp *= __shfl_xor(pp, m);
    pt *= __shfl_xor(pt, m);
    c += __shfl_xor(c, m);
  }
  if (t == 0)
    wr[n] = (c > 0 && pp > 0.f) ? (pt / fmaxf(pp, 1e-38f)) : 0.f;
  __syncthreads();
  float wsum = 0.f;
#pragma unroll
  for (int m2 = 0; m2 < 16; ++m2) wsum += wr[m2];
  const float wn = (wsum > 0.f) ? (wr[n] / fmaxf(wsum, 1e-38f)) : 0.0625f;
  // scatter wa[k] += w[n] * s[n,k]  (expected ~1 selection per sample)
  for (int j = 0; j < 32; ++j) {
    if ((bits >> j) & 1u) atomicAdd(&wa[t + (j << 4)], wn);
  }
  __syncthreads();
  // normalize wa row
  float sp = wa[tid] + wa[tid + 256];
  for (int m = 1; m < 64; m <<= 1) sp += __shfl_xor(sp, m);
  if ((tid & 63) == 0) redc[tid >> 6] = sp;
  __syncthreads();
  const float was = redc[0] + redc[1] + redc[2] + redc[3];
  for (int k = tid; k < 512; k += 256)
    wa[k] = (was > 0.f) ? (wa[k] / fmaxf(was, 1e-38f)) : 0.001953125f;
  __syncthreads();
  // attn @ V : 4 groups of 64 lanes, each covers 128 k-values for all d
  const int g = tid >> 6, d = tid & 63;
  const float* Vb = V + ((size_t)(b * 8 + h) * 512) * 64;
  float acc = 0.f;
  for (int k2 = g * 128; k2 < g * 128 + 128; ++k2)
    acc = fmaf(wa[k2], Vb[(size_t)k2 * 64 + d], acc);
  psum[g][d] = acc;
  __syncthreads();
  if (g == 0) {
    const float o = psum[0][d] + psum[1][d] + psum[2][d] + psum[3][d];
    ao[((size_t)(b * 512 + q) * 512) + h * 64 + d] = o;   // [B,S,D] layout
  }
}

// ---------------------------------------------------------------------------
extern "C" void kernel_launch(void* const* d_in, const int* in_sizes, int n_in,
                              void* d_out, int out_size, void* d_ws,
                              size_t ws_size, hipStream_t stream) {
  const float* x  = (const float*)d_in[0];
  const float* Wq = (const float*)d_in[1];
  const float* bq = (const float*)d_in[2];
  const float* Wk = (const float*)d_in[3];
  const float* bk = (const float*)d_in[4];
  const float* Wv = (const float*)d_in[5];
  const float* bv = (const float*)d_in[6];
  const float* Wo = (const float*)d_in[7];
  const float* bo = (const float*)d_in[8];
  float* out = (float*)d_out;

  float* ws = (float*)d_ws;
  float* Qw = ws;                  // 524288 f32  [B,H,S,dk]
  float* Kw = ws + 524288;         // 524288
  float* Vw = ws + 1048576;        // 524288
  float* tf = ws + 1572864;        // 4194304    [R=8192, 512]
  float* ao = ws + 5767168;        // 524288     [B,S,D]

  dim3 gq(16, 8, 3);
  qkv_gemm<<<gq, 256, 0, stream>>>(x, Wq, bq, Wk, bk, Wv, bv, Qw, Kw, Vw);
  scores_softmax<<<8192, 256, 0, stream>>>(Qw, Kw, tf);
  sample_attnv<<<8192, 256, 0, stream>>>(tf, Vw, ao);
  dim3 go(16, 8, 1);
  out_gemm<<<go, 256, 0, stream>>>(ao, Wo, bo, out);
}

// Round 3
// 316.452 us; speedup vs baseline: 1.5716x; 1.5716x over previous
//
#include <hip/hip_runtime.h>
#include <cstdint>
#include <cstddef>

// B=2, S=512, D_MODEL=512, H=8, dk=64, N_SAMPLES=16; R = B*H*S = 8192 rows.
// JAX partitionable threefry: bits[i] = o0^o1, (o0,o1)=threefry2x32((0,42),(0,i))
// u = (float)(bits>>9) * 2^-23 ;  select iff u < p  ⟺  (float)(bits>>9) < p*2^23

#if __has_builtin(__builtin_amdgcn_alignbit)
#define ROTL(x, r) __builtin_amdgcn_alignbit((x), (x), 32 - (r))
#else
#define ROTL(x, r) (((x) << (r)) | ((x) >> (32 - (r))))
#endif

// 4 threefry rounds
#define TF4(a, b, c, dd)                                                      \
  x0 += x1; x1 = ROTL(x1, a); x1 ^= x0;                                       \
  x0 += x1; x1 = ROTL(x1, b); x1 ^= x0;                                       \
  x0 += x1; x1 = ROTL(x1, c); x1 ^= x0;                                       \
  x0 += x1; x1 = ROTL(x1, dd); x1 ^= x0;

// Full threefry2x32 with key (0,42); input x1 must ALREADY include +42 (ks[1]).
__device__ __forceinline__ uint32_t threefry_fold_0_42(uint32_t x1pre) {
  uint32_t x0 = 0u, x1 = x1pre;
  TF4(13, 15, 26, 6)  x0 += 42u;          x1 += 0x1BD11BF1u;  // K2+1
  TF4(17, 29, 16, 24) x0 += 0x1BD11BF0u;  x1 += 2u;
  TF4(13, 15, 26, 6)  /* x0 += 0 */       x1 += 45u;          // K1+3
  TF4(17, 29, 16, 24) x0 += 42u;          x1 += 0x1BD11BF4u;  // K2+4
  TF4(13, 15, 26, 6)  x0 += 0x1BD11BF0u;  x1 += 5u;
  return x0 ^ x1;
}

// ---------------------------------------------------------------------------
// Kernel A: QKV projection. grid=(32,8,3), block=256. 32x64 tile, BK=32.
// LDS A transposed ([k][m]) so fragment reads are float2; B is [k][n] float4.
// K-accumulation order identical to prior round (bit-exact Q/K/V).
// ---------------------------------------------------------------------------
__global__ __launch_bounds__(256)
void qkv_gemm(const float* __restrict__ x,
              const float* __restrict__ Wq, const float* __restrict__ bq,
              const float* __restrict__ Wk, const float* __restrict__ bk,
              const float* __restrict__ Wv, const float* __restrict__ bv,
              float* __restrict__ Qw, float* __restrict__ Kw,
              float* __restrict__ Vw) {
  const float* W; const float* bias; float* out;
  if (blockIdx.z == 0)      { W = Wq; bias = bq; out = Qw; }
  else if (blockIdx.z == 1) { W = Wk; bias = bk; out = Kw; }
  else                      { W = Wv; bias = bv; out = Vw; }

  __shared__ float At[32][34];   // [k][m], pad->even stride for float2 reads
  __shared__ float Bs[32][64];   // [k][n]
  const int tid = threadIdx.x;
  const int tx = tid & 15, ty = tid >> 4;       // tx: 4 cols, ty: 2 rows
  const int row0 = blockIdx.x * 32, col0 = blockIdx.y * 64;
  float acc[2][4] = {};

  for (int kk = 0; kk < 512; kk += 32) {
    {
      const int rr = tid >> 3, cc = (tid & 7) << 2;          // A: 1 float4
      float4 a4 = *(const float4*)&x[(size_t)(row0 + rr) * 512 + kk + cc];
      At[cc + 0][rr] = a4.x; At[cc + 1][rr] = a4.y;
      At[cc + 2][rr] = a4.z; At[cc + 3][rr] = a4.w;
#pragma unroll
      for (int ii = 0; ii < 2; ++ii) {                       // B: 2 float4
        const int idx = tid + ii * 256;
        const int brr = idx >> 4, bcc = (idx & 15) << 2;
        *(float4*)&Bs[brr][bcc] =
            *(const float4*)&W[(size_t)(kk + brr) * 512 + col0 + bcc];
      }
    }
    __syncthreads();
#pragma unroll
    for (int p = 0; p < 32; ++p) {
      const float2 a2 = *(const float2*)&At[p][ty * 2];
      const float4 b4 = *(const float4*)&Bs[p][tx * 4];
      acc[0][0] = fmaf(a2.x, b4.x, acc[0][0]); acc[0][1] = fmaf(a2.x, b4.y, acc[0][1]);
      acc[0][2] = fmaf(a2.x, b4.z, acc[0][2]); acc[0][3] = fmaf(a2.x, b4.w, acc[0][3]);
      acc[1][0] = fmaf(a2.y, b4.x, acc[1][0]); acc[1][1] = fmaf(a2.y, b4.y, acc[1][1]);
      acc[1][2] = fmaf(a2.y, b4.z, acc[1][2]); acc[1][3] = fmaf(a2.y, b4.w, acc[1][3]);
    }
    __syncthreads();
  }
#pragma unroll
  for (int i = 0; i < 2; ++i) {
    const int row = row0 + ty * 2 + i;
    const int b = row >> 9, s = row & 511;
#pragma unroll
    for (int j = 0; j < 4; ++j) {
      const int col = col0 + tx * 4 + j;
      const int h = col >> 6, d = col & 63;
      out[(((size_t)(b * 8 + h) * 512 + s) * 64) + d] = acc[i][j] + bias[col];
    }
  }
}

// ---------------------------------------------------------------------------
// Kernel D: output projection. grid=(32,8), 32x64 tile, BK=32.
// ---------------------------------------------------------------------------
__global__ __launch_bounds__(256)
void out_gemm(const float* __restrict__ A, const float* __restrict__ W,
              const float* __restrict__ bias, float* __restrict__ C) {
  __shared__ float At[32][34];
  __shared__ float Bs[32][64];
  const int tid = threadIdx.x;
  const int tx = tid & 15, ty = tid >> 4;
  const int row0 = blockIdx.x * 32, col0 = blockIdx.y * 64;
  float acc[2][4] = {};

  for (int kk = 0; kk < 512; kk += 32) {
    {
      const int rr = tid >> 3, cc = (tid & 7) << 2;
      float4 a4 = *(const float4*)&A[(size_t)(row0 + rr) * 512 + kk + cc];
      At[cc + 0][rr] = a4.x; At[cc + 1][rr] = a4.y;
      At[cc + 2][rr] = a4.z; At[cc + 3][rr] = a4.w;
#pragma unroll
      for (int ii = 0; ii < 2; ++ii) {
        const int idx = tid + ii * 256;
        const int brr = idx >> 4, bcc = (idx & 15) << 2;
        *(float4*)&Bs[brr][bcc] =
            *(const float4*)&W[(size_t)(kk + brr) * 512 + col0 + bcc];
      }
    }
    __syncthreads();
#pragma unroll
    for (int p = 0; p < 32; ++p) {
      const float2 a2 = *(const float2*)&At[p][ty * 2];
      const float4 b4 = *(const float4*)&Bs[p][tx * 4];
      acc[0][0] = fmaf(a2.x, b4.x, acc[0][0]); acc[0][1] = fmaf(a2.x, b4.y, acc[0][1]);
      acc[0][2] = fmaf(a2.x, b4.z, acc[0][2]); acc[0][3] = fmaf(a2.x, b4.w, acc[0][3]);
      acc[1][0] = fmaf(a2.y, b4.x, acc[1][0]); acc[1][1] = fmaf(a2.y, b4.y, acc[1][1]);
      acc[1][2] = fmaf(a2.y, b4.z, acc[1][2]); acc[1][3] = fmaf(a2.y, b4.w, acc[1][3]);
    }
    __syncthreads();
  }
#pragma unroll
  for (int i = 0; i < 2; ++i) {
    const int row = row0 + ty * 2 + i;
#pragma unroll
    for (int j = 0; j < 4; ++j) {
      const int col = col0 + tx * 4 + j;
      C[(size_t)row * 512 + col] = acc[i][j] + bias[col];
    }
  }
}

// ---------------------------------------------------------------------------
// Kernel B: scores + softmax -> tf. 4 q-rows per block (K-row reuse x4).
// grid = 2048: blk = bh*128 + qtile. Dot order identical to prior round.
// ---------------------------------------------------------------------------
__global__ __launch_bounds__(256)
void scores_softmax(const float* __restrict__ Q, const float* __restrict__ Kt,
                    float* __restrict__ tf_g) {
  const int blk = blockIdx.x;
  const int bh = blk >> 7, q0 = (blk & 127) << 2;
  const int tid = threadIdx.x;
  __shared__ __align__(16) float qs[4][64];
  __shared__ float redm[4][4], reds[4][4];
  qs[tid >> 6][tid & 63] =
      Q[((size_t)bh * 512 + q0 + (tid >> 6)) * 64 + (tid & 63)];
  __syncthreads();

  float sc[4][2];
#pragma unroll
  for (int ii = 0; ii < 2; ++ii) {
    const int k = tid + ii * 256;
    const float4* Kp = (const float4*)(Kt + ((size_t)bh * 512 + k) * 64);
    float a0 = 0.f, a1 = 0.f, a2 = 0.f, a3 = 0.f;
#pragma unroll
    for (int d4 = 0; d4 < 16; ++d4) {
      const float4 kv = Kp[d4];
      const float4 v0 = ((const float4*)qs[0])[d4];
      const float4 v1 = ((const float4*)qs[1])[d4];
      const float4 v2 = ((const float4*)qs[2])[d4];
      const float4 v3 = ((const float4*)qs[3])[d4];
      a0 = fmaf(v0.x, kv.x, a0); a0 = fmaf(v0.y, kv.y, a0);
      a0 = fmaf(v0.z, kv.z, a0); a0 = fmaf(v0.w, kv.w, a0);
      a1 = fmaf(v1.x, kv.x, a1); a1 = fmaf(v1.y, kv.y, a1);
      a1 = fmaf(v1.z, kv.z, a1); a1 = fmaf(v1.w, kv.w, a1);
      a2 = fmaf(v2.x, kv.x, a2); a2 = fmaf(v2.y, kv.y, a2);
      a2 = fmaf(v2.z, kv.z, a2); a2 = fmaf(v2.w, kv.w, a2);
      a3 = fmaf(v3.x, kv.x, a3); a3 = fmaf(v3.y, kv.y, a3);
      a3 = fmaf(v3.z, kv.z, a3); a3 = fmaf(v3.w, kv.w, a3);
    }
    sc[0][ii] = a0 * 0.125f; sc[1][ii] = a1 * 0.125f;
    sc[2][ii] = a2 * 0.125f; sc[3][ii] = a3 * 0.125f;
  }
  float mx[4];
#pragma unroll
  for (int i = 0; i < 4; ++i) mx[i] = fmaxf(sc[i][0], sc[i][1]);
  for (int m = 1; m < 64; m <<= 1) {
#pragma unroll
    for (int i = 0; i < 4; ++i) mx[i] = fmaxf(mx[i], __shfl_xor(mx[i], m));
  }
  if ((tid & 63) == 0) {
    const int w = tid >> 6;
#pragma unroll
    for (int i = 0; i < 4; ++i) redm[i][w] = mx[i];
  }
  __syncthreads();
  float ex[4][2], sm[4];
#pragma unroll
  for (int i = 0; i < 4; ++i) {
    const float rm = fmaxf(fmaxf(redm[i][0], redm[i][1]),
                           fmaxf(redm[i][2], redm[i][3]));
    ex[i][0] = expf(sc[i][0] - rm);
    ex[i][1] = expf(sc[i][1] - rm);
    sm[i] = ex[i][0] + ex[i][1];
  }
  for (int m = 1; m < 64; m <<= 1) {
#pragma unroll
    for (int i = 0; i < 4; ++i) sm[i] += __shfl_xor(sm[i], m);
  }
  if ((tid & 63) == 0) {
    const int w = tid >> 6;
#pragma unroll
    for (int i = 0; i < 4; ++i) reds[i][w] = sm[i];
  }
  __syncthreads();
#pragma unroll
  for (int i = 0; i < 4; ++i) {
    const float tot = reds[i][0] + reds[i][1] + reds[i][2] + reds[i][3];
    tf_g[((size_t)bh * 512 + q0 + i) * 512 + tid]       = ex[i][0] / tot;
    tf_g[((size_t)bh * 512 + q0 + i) * 512 + tid + 256] = ex[i][1] / tot;
  }
}

// ---------------------------------------------------------------------------
// Kernel C: sampling + sparse weighted attn@V.  One block per row r.
// 256 threads = 16 samples x 16 lanes; lane covers k = t + 16j, j<32.
// Hot loop: threefry + int-domain Bernoulli compare + bitmask only.
// ---------------------------------------------------------------------------
__global__ __launch_bounds__(256)
void sample_attnv(const float* __restrict__ tf_g, const float* __restrict__ V,
                  float* __restrict__ ao) {
  const int r = blockIdx.x;                   // 0..8191
  const int b = r >> 12, h = (r >> 9) & 7, q = r & 511;
  const int tid = threadIdx.x;
  __shared__ float tf[512];
  __shared__ float psc[512];                  // p * 2^23 (exact)
  __shared__ float wa[512];
  __shared__ float wr[16];
  __shared__ float redc[8];
  __shared__ float psum[4][64];
  __shared__ int   list[512];
  __shared__ int   cnt;

  if (tid == 0) cnt = 0;
  for (int k = tid; k < 512; k += 256) {
    const float tv = tf_g[(size_t)r * 512 + k];
    tf[k] = tv;
    const float p = fmaf(0.5f, tv, 0.0009765625f);
    psc[k] = p * 8388608.0f;
    wa[k] = 0.f;
  }
  __syncthreads();

  // Qrow = prod_k (1 - p_k)   (block-wide product)
  {
    const float p1 = fmaf(0.5f, tf[tid], 0.0009765625f);
    const float p2 = fmaf(0.5f, tf[tid + 256], 0.0009765625f);
    float ql = (1.f - p1) * (1.f - p2);
    for (int m = 1; m < 64; m <<= 1) ql *= __shfl_xor(ql, m);
    if ((tid & 63) == 0) redc[4 + (tid >> 6)] = ql;
  }
  __syncthreads();
  const float Qrow = redc[4] * redc[5] * redc[6] * redc[7];

  const int n = tid >> 4, t = tid & 15;
  // counter pre-offset by ks[1]=42; element i = r*8192 + n*512 + t + 16j
  const uint32_t cnt42 =
      (uint32_t)r * 8192u + (uint32_t)n * 512u + (uint32_t)t + 42u;
  uint32_t bits = 0u;
#pragma unroll 8
  for (int j = 0; j < 32; ++j) {
    const uint32_t rb = threefry_fold_0_42(cnt42 + (uint32_t)(j << 4));
    const float f = (float)(rb >> 9);         // exact 23-bit
    const bool s = f < psc[t + (j << 4)];
    bits |= (s ? 1u : 0u) << j;
  }

  // rare path: selected-term products
  float ptl = 1.f, ratl = 1.f;
  int cl = __popc(bits);
  {
    uint32_t bb = bits;
    while (bb) {
      const int j = __builtin_ctz(bb);
      bb &= bb - 1u;
      const float tv = tf[t + (j << 4)];
      const float p = fmaf(0.5f, tv, 0.0009765625f);
      ptl *= tv;
      ratl *= p / (1.f - p);
    }
  }
#pragma unroll
  for (int m = 1; m < 16; m <<= 1) {
    ptl *= __shfl_xor(ptl, m);
    ratl *= __shfl_xor(ratl, m);
    cl += __shfl_xor(cl, m);
  }
  if (t == 0) {
    const float pp = Qrow * ratl;
    wr[n] = (cl > 0 && pp > 0.f) ? (ptl / fmaxf(pp, 1e-38f)) : 0.f;
  }
  __syncthreads();
  float wsum = 0.f;
#pragma unroll
  for (int m2 = 0; m2 < 16; ++m2) wsum += wr[m2];
  const float wn = (wsum > 0.f) ? (wr[n] / fmaxf(wsum, 1e-38f)) : 0.0625f;
  {
    uint32_t bb = bits;
    while (bb) {
      const int j = __builtin_ctz(bb);
      bb &= bb - 1u;
      atomicAdd(&wa[t + (j << 4)], wn);
    }
  }
  __syncthreads();

  // row sum + compact nonzeros
  float sp = wa[tid] + wa[tid + 256];
  for (int m = 1; m < 64; m <<= 1) sp += __shfl_xor(sp, m);
  if ((tid & 63) == 0) redc[tid >> 6] = sp;
  if (wa[tid] > 0.f)       { const int i = atomicAdd(&cnt, 1); list[i] = tid; }
  if (wa[tid + 256] > 0.f) { const int i = atomicAdd(&cnt, 1); list[i] = tid + 256; }
  __syncthreads();
  const float was = redc[0] + redc[1] + redc[2] + redc[3];
  const int nnz = cnt;

  // sparse attn @ V over ~16 nonzero k
  const int g = tid >> 6, d = tid & 63;
  const float* Vb = V + ((size_t)(b * 8 + h) * 512) * 64;
  float acc = 0.f;
  if (was > 0.f) {
    const float inv = 1.f / fmaxf(was, 1e-38f);
    for (int i = g; i < nnz; i += 4) {
      const int k = list[i];
      acc = fmaf(wa[k] * inv, Vb[(size_t)k * 64 + d], acc);
    }
  } else {
    for (int k = g; k < 512; k += 4) acc += Vb[(size_t)k * 64 + d];
    acc *= 0.001953125f;
  }
  psum[g][d] = acc;
  __syncthreads();
  if (g == 0) {
    ao[((size_t)(b * 512 + q) * 512) + h * 64 + d] =
        psum[0][d] + psum[1][d] + psum[2][d] + psum[3][d];
  }
}

// ---------------------------------------------------------------------------
extern "C" void kernel_launch(void* const* d_in, const int* in_sizes, int n_in,
                              void* d_out, int out_size, void* d_ws,
                              size_t ws_size, hipStream_t stream) {
  const float* x  = (const float*)d_in[0];
  const float* Wq = (const float*)d_in[1];
  const float* bq = (const float*)d_in[2];
  const float* Wk = (const float*)d_in[3];
  const float* bk = (const float*)d_in[4];
  const float* Wv = (const float*)d_in[5];
  const float* bv = (const float*)d_in[6];
  const float* Wo = (const float*)d_in[7];
  const float* bo = (const float*)d_in[8];
  float* out = (float*)d_out;

  float* ws = (float*)d_ws;
  float* Qw = ws;                  // 524288 f32  [B,H,S,dk]
  float* Kw = ws + 524288;         // 524288
  float* Vw = ws + 1048576;        // 524288
  float* tf = ws + 1572864;        // 4194304    [R=8192, 512]
  float* ao = ws + 5767168;        // 524288     [B,S,D]

  dim3 gq(32, 8, 3);
  qkv_gemm<<<gq, 256, 0, stream>>>(x, Wq, bq, Wk, bk, Wv, bv, Qw, Kw, Vw);
  scores_softmax<<<2048, 256, 0, stream>>>(Qw, Kw, tf);
  sample_attnv<<<8192, 256, 0, stream>>>(tf, Vw, ao);
  dim3 go(32, 8);
  out_gemm<<<go, 256, 0, stream>>>(ao, Wo, bo, out);
}